// Round 10
// baseline (9648.412 us; speedup 1.0000x reference)
//
#include <hip/hip_runtime.h>

#define DI __device__ __forceinline__

typedef float f32x4 __attribute__((ext_vector_type(4)));
typedef unsigned short u16;
typedef u16 u16x8 __attribute__((ext_vector_type(8)));
typedef u16 u16x4 __attribute__((ext_vector_type(4)));
typedef __bf16 bf16x8 __attribute__((ext_vector_type(8)));

DI u16 f2bf(float f) {
    unsigned u = __builtin_bit_cast(unsigned, f);
    u += 0x7fffu + ((u >> 16) & 1u);
    return (u16)(u >> 16);
}

DI float bf2f(u16 b) {
    unsigned u = ((unsigned)b) << 16;
    return __builtin_bit_cast(float, u);
}

DI f32x4 mfma_bf16(u16x8 a, u16x8 b, f32x4 c) {
    return __builtin_amdgcn_mfma_f32_16x16x32_bf16(
        __builtin_bit_cast(bf16x8, a), __builtin_bit_cast(bf16x8, b), c, 0, 0, 0);
}

DI void gload_lds16(const void* g, void* l) {
    __builtin_amdgcn_global_load_lds(
        (const __attribute__((address_space(1))) unsigned int*)g,
        (__attribute__((address_space(3))) unsigned int*)l, 16, 0, 0);
}

// ---------------- cast x -> bf16 ----------------
__global__ __launch_bounds__(256) void k_cast_x(const float* __restrict__ x, u16* __restrict__ xb) {
    size_t i = (size_t)blockIdx.x * 256 + threadIdx.x;  // 8 elems each
    const f32x4* p = (const f32x4*)(x + i * 8);
    f32x4 a = p[0], b = p[1];
    u16x8 o;
    o[0] = f2bf(a[0]); o[1] = f2bf(a[1]); o[2] = f2bf(a[2]); o[3] = f2bf(a[3]);
    o[4] = f2bf(b[0]); o[5] = f2bf(b[1]); o[6] = f2bf(b[2]); o[7] = f2bf(b[3]);
    *(u16x8*)(xb + i * 8) = o;
}

// ---------------- transpose Wqkv [768,2304] -> Wt bf16 [2304,768] ----------------
__global__ __launch_bounds__(256) void k_transpose_w(const float* __restrict__ W, u16* __restrict__ Wt) {
    __shared__ float tile[64][65];
    const int t = threadIdx.x;
    const int nb = blockIdx.x * 64, kb = blockIdx.y * 64;
#pragma unroll
    for (int it = 0; it < 4; ++it) {
        int idx = it * 256 + t;
        int kl = idx >> 4, nl4 = (idx & 15) * 4;
        f32x4 v = *(const f32x4*)(W + (size_t)(kb + kl) * 2304 + nb + nl4);
        tile[kl][nl4 + 0] = v[0]; tile[kl][nl4 + 1] = v[1];
        tile[kl][nl4 + 2] = v[2]; tile[kl][nl4 + 3] = v[3];
    }
    __syncthreads();
#pragma unroll
    for (int it = 0; it < 2; ++it) {
        int idx = it * 256 + t;
        int nl = idx >> 3, kc = (idx & 7) * 8;
        u16x8 o;
#pragma unroll
        for (int j = 0; j < 8; ++j) o[j] = f2bf(tile[kc + j][nl]);
        *(u16x8*)(Wt + (size_t)(nb + nl) * 768 + kb + kc) = o;
    }
}

// ---------------- QKV GEMM (reps arg for measurement; idempotent) ----------------
__global__ __launch_bounds__(256, 2) void k_qkvR(const u16* __restrict__ A, const u16* __restrict__ Bt,
                                                 const float* __restrict__ pos, u16* __restrict__ Qb,
                                                 u16* __restrict__ Kb, u16* __restrict__ Vt, int reps) {
    __shared__ __align__(16) union SM {
        u16 stage[2][2][8192];  // [buf][A/B][128 rows x 64 k]
        u16 vt[128][136];       // epilogue transpose tile (rows 16B-aligned: 272B)
    } sm;
    const int tid = threadIdx.x;
    const int l = tid & 63, w = tid >> 6;
    const int wm = w >> 1, wn = w & 1;
    const int m0 = blockIdx.x * 128, n0 = blockIdx.y * 128;
    const int srow = l >> 3, sslot = (l & 7) ^ srow;
    const int q4 = l >> 4, lr = l & 15;

    for (int rep = 0; rep < reps; ++rep) {
        f32x4 acc[4][4];
#pragma unroll
        for (int i = 0; i < 4; ++i)
#pragma unroll
            for (int j = 0; j < 4; ++j) acc[i][j] = (f32x4){0.f, 0.f, 0.f, 0.f};

        const size_t abase = (size_t)(m0 + srow) * 768 + sslot * 8;
        const size_t bbase = (size_t)(n0 + srow) * 768 + sslot * 8;

#pragma unroll
        for (int i = 0; i < 4; ++i) {
            int chunk = w * 4 + i;
            gload_lds16(A + abase + (size_t)chunk * 8 * 768, &sm.stage[0][0][chunk * 512]);
            gload_lds16(Bt + bbase + (size_t)chunk * 8 * 768, &sm.stage[0][1][chunk * 512]);
        }
        __syncthreads();

        int cur = 0;
        for (int kt = 0; kt < 12; ++kt) {
            if (kt < 11) {
                const size_t ko = (size_t)(kt + 1) * 64;
#pragma unroll
                for (int i = 0; i < 4; ++i) {
                    int chunk = w * 4 + i;
                    gload_lds16(A + abase + (size_t)chunk * 8 * 768 + ko, &sm.stage[cur ^ 1][0][chunk * 512]);
                    gload_lds16(Bt + bbase + (size_t)chunk * 8 * 768 + ko, &sm.stage[cur ^ 1][1][chunk * 512]);
                }
            }
            const u16* ab = sm.stage[cur][0];
            const u16* bb = sm.stage[cur][1];
            u16x8 af[4][2], bf[4][2];
#pragma unroll
            for (int mi = 0; mi < 4; ++mi) {
                int row = wm * 64 + mi * 16 + lr;
#pragma unroll
                for (int ks = 0; ks < 2; ++ks) {
                    int kc = ks * 4 + q4;
                    af[mi][ks] = *(const u16x8*)(ab + row * 64 + (kc ^ (row & 7)) * 8);
                }
            }
#pragma unroll
            for (int ni = 0; ni < 4; ++ni) {
                int row = wn * 64 + ni * 16 + lr;
#pragma unroll
                for (int ks = 0; ks < 2; ++ks) {
                    int kc = ks * 4 + q4;
                    bf[ni][ks] = *(const u16x8*)(bb + row * 64 + (kc ^ (row & 7)) * 8);
                }
            }
#pragma unroll
            for (int mi = 0; mi < 4; ++mi)
#pragma unroll
                for (int ni = 0; ni < 4; ++ni) {
                    acc[mi][ni] = mfma_bf16(af[mi][0], bf[ni][0], acc[mi][ni]);
                    acc[mi][ni] = mfma_bf16(af[mi][1], bf[ni][1], acc[mi][ni]);
                }
            __syncthreads();
            cur ^= 1;
        }

        const int sec = blockIdx.y / 6;
        const int dsec = n0 - sec * 768;
        const int bidx = m0 >> 10;
        const int prow = m0 & 1023;
        if (sec < 2) {
            u16* outp = sec ? Kb : Qb;
#pragma unroll
            for (int mi = 0; mi < 4; ++mi)
#pragma unroll
                for (int ni = 0; ni < 4; ++ni) {
                    const int dl = wn * 64 + ni * 16 + lr;
                    const int d = dsec + dl;
#pragma unroll
                    for (int r = 0; r < 4; ++r) {
                        const int pl = wm * 64 + mi * 16 + q4 * 4 + r;
                        const int p = prow + pl;
                        sm.vt[pl][dl] = f2bf(acc[mi][ni][r] + pos[p * 768 + d]);
                    }
                }
            __syncthreads();
#pragma unroll
            for (int it = 0; it < 8; ++it) {
                const int idx = it * 256 + tid;
                const int pl = idx >> 4, c8 = (idx & 15) * 8;
                u16x8 val = *(const u16x8*)(&sm.vt[pl][c8]);
                const int d = dsec + c8, h = d >> 6, hd = d & 63;
                *(u16x8*)(outp + (size_t)((bidx * 12 + h) * 1024 + prow + pl) * 64 + hd) = val;
            }
        } else {
#pragma unroll
            for (int mi = 0; mi < 4; ++mi)
#pragma unroll
                for (int ni = 0; ni < 4; ++ni) {
                    int col = wn * 64 + ni * 16 + lr;
                    int d = dsec + col;
                    u16x4 pk;
#pragma unroll
                    for (int r = 0; r < 4; ++r) {
                        int p = prow + wm * 64 + mi * 16 + q4 * 4 + r;
                        pk[r] = f2bf(acc[mi][ni][r] + pos[p * 768 + d]);
                    }
                    *(u16x4*)(&sm.vt[col][wm * 64 + mi * 16 + q4 * 4]) = pk;
                }
            __syncthreads();
#pragma unroll
            for (int it = 0; it < 8; ++it) {
                int idx = it * 256 + tid;
                int dl = idx >> 4, c8 = (idx & 15) * 8;
                u16x8 val = *(const u16x8*)(&sm.vt[dl][c8]);
                int d = dsec + dl, h = d >> 6, hd = d & 63;
                *(u16x8*)(Vt + (size_t)((bidx * 12 + h) * 64 + hd) * 1024 + prow + c8) = val;
            }
        }
        __syncthreads();  // protect sm union before next rep's staging
    }
}

// ---------------- attn body (shared by variants + production) ----------------
template <bool NT>
DI void attn_body(const u16* __restrict__ Qb, const u16* __restrict__ Kb,
                  const u16* __restrict__ Vt, float* __restrict__ Pout,
                  float* __restrict__ pooled, int reps,
                  u16 (*P_lds)[16][64], float* stats) {
    const int tid = threadIdx.x;
    const int l = tid & 63, w = tid >> 6;
    const int lr = l & 15, q4 = l >> 4;
    const int bh = blockIdx.y, q0 = blockIdx.x * 16;
    const u16* Qh = Qb + (size_t)bh * 65536;
    const u16* Kh = Kb + (size_t)bh * 65536;
    const u16* Vh = Vt + (size_t)bh * 65536;

    for (int rep = 0; rep < reps; ++rep) {
        u16x8 qf[2];
#pragma unroll
        for (int ks = 0; ks < 2; ++ks)
            qf[ks] = *(const u16x8*)(Qh + (size_t)(q0 + lr) * 64 + ks * 32 + q4 * 8);

        f32x4 acc[16];
#pragma unroll
        for (int nf = 0; nf < 16; ++nf) acc[nf] = (f32x4){0.f, 0.f, 0.f, 0.f};

        const int kc0 = w * 256;
#pragma unroll
        for (int nf = 0; nf < 16; ++nf) {
            const u16* kp = Kh + (size_t)(kc0 + nf * 16 + lr) * 64 + q4 * 8;
            u16x8 kf0 = *(const u16x8*)kp;
            u16x8 kf1 = *(const u16x8*)(kp + 32);
            acc[nf] = mfma_bf16(qf[0], kf0, acc[nf]);
            acc[nf] = mfma_bf16(qf[1], kf1, acc[nf]);
        }

        float mx[4], inv4[4];
#pragma unroll
        for (int r = 0; r < 4; ++r) {
            float m = acc[0][r];
#pragma unroll
            for (int nf = 1; nf < 16; ++nf) m = fmaxf(m, acc[nf][r]);
            m = fmaxf(m, __shfl_xor(m, 1));
            m = fmaxf(m, __shfl_xor(m, 2));
            m = fmaxf(m, __shfl_xor(m, 4));
            m = fmaxf(m, __shfl_xor(m, 8));
            if (lr == 0) stats[(q4 * 4 + r) * 4 + w] = m;
        }
        __syncthreads();
#pragma unroll
        for (int r = 0; r < 4; ++r) {
            f32x4 s4 = *(const f32x4*)(stats + (q4 * 4 + r) * 4);
            mx[r] = fmaxf(fmaxf(s4[0], s4[1]), fmaxf(s4[2], s4[3]));
        }

        const float cs = 0.125f * 1.44269504f;
#pragma unroll
        for (int r = 0; r < 4; ++r) {
            float s = 0.f;
#pragma unroll
            for (int nf = 0; nf < 16; ++nf) {
                float e = exp2f((acc[nf][r] - mx[r]) * cs);
                acc[nf][r] = e;
                s += e;
            }
            s += __shfl_xor(s, 1);
            s += __shfl_xor(s, 2);
            s += __shfl_xor(s, 4);
            s += __shfl_xor(s, 8);
            if (lr == 0) stats[64 + (q4 * 4 + r) * 4 + w] = s;
        }
        __syncthreads();
#pragma unroll
        for (int r = 0; r < 4; ++r) {
            f32x4 s4 = *(const f32x4*)(stats + 64 + (q4 * 4 + r) * 4);
            inv4[r] = 1.f / (s4[0] + s4[1] + s4[2] + s4[3]);
        }

        float* Pbase = Pout + ((size_t)bh * 1024 + q0) * 1024 + kc0;
        f32x4 acc2[4];
#pragma unroll
        for (int nd = 0; nd < 4; ++nd) acc2[nd] = (f32x4){0.f, 0.f, 0.f, 0.f};
        const int swa = (lr & 7) << 3;
        const int scol = lr * 4;

#pragma unroll
        for (int c = 0; c < 4; ++c) {
#pragma unroll
            for (int r = 0; r < 4; ++r) {
                const int row = q4 * 4 + r;
                const int sw = (row & 7) << 3;
                const float iv = inv4[r];
#pragma unroll
                for (int nfl = 0; nfl < 4; ++nfl) {
                    const int nf = c * 4 + nfl;
                    P_lds[w][row][(nfl * 16 + lr) ^ sw] = f2bf(acc[nf][r] * iv);
                }
            }
#pragma unroll
            for (int t = 0; t < 4; ++t) {
                const int row = t * 4 + q4;
                const int sw = (row & 7) << 3;
                u16x4 pb = *(const u16x4*)(&P_lds[w][row][scol ^ sw]);
                f32x4 pf = {bf2f(pb[0]), bf2f(pb[1]), bf2f(pb[2]), bf2f(pb[3])};
                if (NT)
                    __builtin_nontemporal_store(pf, (f32x4*)(Pbase + (size_t)row * 1024 + c * 64 + scol));
                else
                    *(f32x4*)(Pbase + (size_t)row * 1024 + c * 64 + scol) = pf;
            }
            const u16* vb = Vh + kc0 + c * 64 + q4 * 8;
#pragma unroll
            for (int ks = 0; ks < 2; ++ks) {
                u16x8 a = *(const u16x8*)(&P_lds[w][lr][(ks * 32 + q4 * 8) ^ swa]);
#pragma unroll
                for (int nd = 0; nd < 4; ++nd) {
                    u16x8 b = *(const u16x8*)(vb + (size_t)(nd * 16 + lr) * 1024 + ks * 32);
                    acc2[nd] = mfma_bf16(a, b, acc2[nd]);
                }
            }
        }

        const int bb = bh / 12, hh = bh % 12;
#pragma unroll
        for (int nd = 0; nd < 4; ++nd) {
            float s = acc2[nd][0] + acc2[nd][1] + acc2[nd][2] + acc2[nd][3];
            s += __shfl_xor(s, 16);
            s += __shfl_xor(s, 32);
            if (l < 16) atomicAdd(pooled + bb * 768 + hh * 64 + nd * 16 + l, s);
        }
        __syncthreads();  // stats reuse next rep
    }
}

// Variant A: current config (lb 4, nt stores)
__global__ __launch_bounds__(256, 4) void k_attnA(const u16* Qb, const u16* Kb, const u16* Vt,
                                                  float* Pout, float* pooled, int reps) {
    __shared__ __align__(16) u16 P_lds[4][16][64];
    __shared__ float stats[128];
    attn_body<true>(Qb, Kb, Vt, Pout, pooled, reps, P_lds, stats);
}
// Variant B: relaxed register cap (lb 2) — spill probe
__global__ __launch_bounds__(256, 2) void k_attnB(const u16* Qb, const u16* Kb, const u16* Vt,
                                                  float* Pout, float* pooled, int reps) {
    __shared__ __align__(16) u16 P_lds[4][16][64];
    __shared__ float stats[128];
    attn_body<true>(Qb, Kb, Vt, Pout, pooled, reps, P_lds, stats);
}
// Variant C: plain stores — nt probe
__global__ __launch_bounds__(256, 4) void k_attnC(const u16* Qb, const u16* Kb, const u16* Vt,
                                                  float* Pout, float* pooled, int reps) {
    __shared__ __align__(16) u16 P_lds[4][16][64];
    __shared__ float stats[128];
    attn_body<false>(Qb, Kb, Vt, Pout, pooled, reps, P_lds, stats);
}
// Production (exact R6 config)
__global__ __launch_bounds__(256, 4) void k_attn(const u16* Qb, const u16* Kb, const u16* Vt,
                                                 float* Pout, float* pooled, int reps) {
    __shared__ __align__(16) u16 P_lds[4][16][64];
    __shared__ float stats[128];
    attn_body<true>(Qb, Kb, Vt, Pout, pooled, reps, P_lds, stats);
}

// ---------------- pooled/1024 @ Wo + bo -> tmp[16,768] ----------------
__global__ __launch_bounds__(128) void k_proj(const float* __restrict__ pooled_sum,
                                              const float* __restrict__ Wo, const float* __restrict__ bo,
                                              float* __restrict__ tmp) {
    const int b = blockIdx.y, j = blockIdx.x * 128 + threadIdx.x;
    __shared__ float pr[768];
    for (int i = threadIdx.x; i < 768; i += 128) pr[i] = pooled_sum[b * 768 + i] * (1.0f / 1024.0f);
    __syncthreads();
    float s = bo[j];
#pragma unroll 4
    for (int d = 0; d < 768; ++d) s = fmaf(pr[d], Wo[d * 768 + j], s);
    tmp[b * 768 + j] = s;
}

// ---------------- tmp @ Wc + bc -> logits ----------------
__global__ __launch_bounds__(128) void k_cls(const float* __restrict__ tmp,
                                             const float* __restrict__ Wc, const float* __restrict__ bc,
                                             float* __restrict__ out) {
    const int b = blockIdx.y, c = blockIdx.x * 128 + threadIdx.x;
    __shared__ float tr[768];
    for (int i = threadIdx.x; i < 768; i += 128) tr[i] = tmp[b * 768 + i];
    __syncthreads();
    if (c >= 1000) return;
    float s = bc[c];
#pragma unroll 4
    for (int j = 0; j < 768; ++j) s = fmaf(tr[j], Wc[j * 1000 + c], s);
    out[b * 1000 + c] = s;
}

extern "C" void kernel_launch(void* const* d_in, const int* in_sizes, int n_in,
                              void* d_out, int out_size, void* d_ws, size_t ws_size,
                              hipStream_t stream) {
    const float* x    = (const float*)d_in[0];
    const float* Wqkv = (const float*)d_in[1];
    const float* pos  = (const float*)d_in[2];
    const float* Wo   = (const float*)d_in[3];
    const float* bo   = (const float*)d_in[4];
    const float* Wc   = (const float*)d_in[5];
    const float* bc   = (const float*)d_in[6];
    float* out  = (float*)d_out;
    float* attn = out + 16000;  // logits [16,1000] first, then attn_weights [16,12,1024,1024]

    char* ws = (char*)d_ws;
    u16* xb = (u16*)ws;  ws += (size_t)16384 * 768 * 2;
    u16* Wt = (u16*)ws;  ws += (size_t)2304 * 768 * 2;
    u16* Qb = (u16*)ws;  ws += (size_t)192 * 1024 * 64 * 2;
    u16* Kb = (u16*)ws;  ws += (size_t)192 * 1024 * 64 * 2;
    u16* Vt = (u16*)ws;  ws += (size_t)192 * 1024 * 64 * 2;
    float* pooled = (float*)ws;  ws += 16 * 768 * sizeof(float);
    float* tmp = (float*)ws;

    // MEASUREMENT ROUND 2: qkv x3-fused + attn variants A/B/C x2-fused (all >500us
    // -> visible in top-5 with counters). Production result from final passes.
    k_cast_x<<<6144, 256, 0, stream>>>(x, xb);
    k_transpose_w<<<dim3(36, 12), 256, 0, stream>>>(Wqkv, Wt);
    k_qkvR<<<dim3(128, 18), 256, 0, stream>>>(xb, Wt, pos, Qb, Kb, Vt, 3);
    k_attnA<<<dim3(64, 192), 256, 0, stream>>>(Qb, Kb, Vt, attn, pooled, 2);
    k_attnB<<<dim3(64, 192), 256, 0, stream>>>(Qb, Kb, Vt, attn, pooled, 2);
    k_attnC<<<dim3(64, 192), 256, 0, stream>>>(Qb, Kb, Vt, attn, pooled, 2);
    hipMemsetAsync(pooled, 0, 16 * 768 * sizeof(float), stream);
    k_attn<<<dim3(64, 192), 256, 0, stream>>>(Qb, Kb, Vt, attn, pooled, 1);
    k_proj<<<dim3(6, 16), 128, 0, stream>>>(pooled, Wo, bo, tmp);
    k_cls<<<dim3(8, 16), 128, 0, stream>>>(tmp, Wc, bc, out);
}

// Round 11
// 2148.847 us; speedup vs baseline: 4.4900x; 4.4900x over previous
//
#include <hip/hip_runtime.h>

#define DI __device__ __forceinline__

typedef float f32x4 __attribute__((ext_vector_type(4)));
typedef unsigned short u16;
typedef u16 u16x8 __attribute__((ext_vector_type(8)));
typedef u16 u16x4 __attribute__((ext_vector_type(4)));
typedef __bf16 bf16x8 __attribute__((ext_vector_type(8)));

DI u16 f2bf(float f) {
    unsigned u = __builtin_bit_cast(unsigned, f);
    u += 0x7fffu + ((u >> 16) & 1u);
    return (u16)(u >> 16);
}

DI float bf2f(u16 b) {
    unsigned u = ((unsigned)b) << 16;
    return __builtin_bit_cast(float, u);
}

DI f32x4 mfma_bf16(u16x8 a, u16x8 b, f32x4 c) {
    return __builtin_amdgcn_mfma_f32_16x16x32_bf16(
        __builtin_bit_cast(bf16x8, a), __builtin_bit_cast(bf16x8, b), c, 0, 0, 0);
}

DI void gload_lds16(const void* g, void* l) {
    __builtin_amdgcn_global_load_lds(
        (const __attribute__((address_space(1))) unsigned int*)g,
        (__attribute__((address_space(3))) unsigned int*)l, 16, 0, 0);
}

DI float fast_exp2(float x) {
    float e;
    asm("v_exp_f32 %0, %1" : "=v"(e) : "v"(x));
    return e;
}

// ---------------- cast x -> bf16 ----------------
__global__ __launch_bounds__(256) void k_cast_x(const float* __restrict__ x, u16* __restrict__ xb) {
    size_t i = (size_t)blockIdx.x * 256 + threadIdx.x;  // 8 elems each
    const f32x4* p = (const f32x4*)(x + i * 8);
    f32x4 a = p[0], b = p[1];
    u16x8 o;
    o[0] = f2bf(a[0]); o[1] = f2bf(a[1]); o[2] = f2bf(a[2]); o[3] = f2bf(a[3]);
    o[4] = f2bf(b[0]); o[5] = f2bf(b[1]); o[6] = f2bf(b[2]); o[7] = f2bf(b[3]);
    *(u16x8*)(xb + i * 8) = o;
}

// ---------------- transpose Wqkv [768,2304] -> Wt bf16 [2304,768] ----------------
__global__ __launch_bounds__(256) void k_transpose_w(const float* __restrict__ W, u16* __restrict__ Wt) {
    __shared__ float tile[64][65];
    const int t = threadIdx.x;
    const int nb = blockIdx.x * 64, kb = blockIdx.y * 64;
#pragma unroll
    for (int it = 0; it < 4; ++it) {
        int idx = it * 256 + t;
        int kl = idx >> 4, nl4 = (idx & 15) * 4;
        f32x4 v = *(const f32x4*)(W + (size_t)(kb + kl) * 2304 + nb + nl4);
        tile[kl][nl4 + 0] = v[0]; tile[kl][nl4 + 1] = v[1];
        tile[kl][nl4 + 2] = v[2]; tile[kl][nl4 + 3] = v[3];
    }
    __syncthreads();
#pragma unroll
    for (int it = 0; it < 2; ++it) {
        int idx = it * 256 + t;
        int nl = idx >> 3, kc = (idx & 7) * 8;
        u16x8 o;
#pragma unroll
        for (int j = 0; j < 8; ++j) o[j] = f2bf(tile[kc + j][nl]);
        *(u16x8*)(Wt + (size_t)(nb + nl) * 768 + kb + kc) = o;
    }
}

// ---------------- QKV GEMM: xb[16384,768] @ Wt^T -> Q,K [B,H,P,64], Vt [B,H,64,P] ----------------
__global__ __launch_bounds__(256, 2) void k_qkv(const u16* __restrict__ A, const u16* __restrict__ Bt,
                                                const float* __restrict__ pos, u16* __restrict__ Qb,
                                                u16* __restrict__ Kb, u16* __restrict__ Vt) {
    __shared__ __align__(16) union SM {
        u16 stage[2][2][8192];  // [buf][A/B][128 rows x 64 k]
        u16 vt[128][136];       // epilogue transpose tile (rows 16B-aligned: 272B)
    } sm;
    const int tid = threadIdx.x;
    const int l = tid & 63, w = tid >> 6;
    const int wm = w >> 1, wn = w & 1;
    const int m0 = blockIdx.x * 128, n0 = blockIdx.y * 128;
    const int srow = l >> 3, sslot = (l & 7) ^ srow;
    const int q4 = l >> 4, lr = l & 15;

    f32x4 acc[4][4];
#pragma unroll
    for (int i = 0; i < 4; ++i)
#pragma unroll
        for (int j = 0; j < 4; ++j) acc[i][j] = (f32x4){0.f, 0.f, 0.f, 0.f};

    const size_t abase = (size_t)(m0 + srow) * 768 + sslot * 8;
    const size_t bbase = (size_t)(n0 + srow) * 768 + sslot * 8;

    // prologue stage kt=0
#pragma unroll
    for (int i = 0; i < 4; ++i) {
        int chunk = w * 4 + i;
        gload_lds16(A + abase + (size_t)chunk * 8 * 768, &sm.stage[0][0][chunk * 512]);
        gload_lds16(Bt + bbase + (size_t)chunk * 8 * 768, &sm.stage[0][1][chunk * 512]);
    }
    __syncthreads();

    int cur = 0;
    for (int kt = 0; kt < 12; ++kt) {
        if (kt < 11) {
            const size_t ko = (size_t)(kt + 1) * 64;
#pragma unroll
            for (int i = 0; i < 4; ++i) {
                int chunk = w * 4 + i;
                gload_lds16(A + abase + (size_t)chunk * 8 * 768 + ko, &sm.stage[cur ^ 1][0][chunk * 512]);
                gload_lds16(Bt + bbase + (size_t)chunk * 8 * 768 + ko, &sm.stage[cur ^ 1][1][chunk * 512]);
            }
        }
        const u16* ab = sm.stage[cur][0];
        const u16* bb = sm.stage[cur][1];
        u16x8 af[4][2], bf[4][2];
#pragma unroll
        for (int mi = 0; mi < 4; ++mi) {
            int row = wm * 64 + mi * 16 + lr;
#pragma unroll
            for (int ks = 0; ks < 2; ++ks) {
                int kc = ks * 4 + q4;
                af[mi][ks] = *(const u16x8*)(ab + row * 64 + (kc ^ (row & 7)) * 8);
            }
        }
#pragma unroll
        for (int ni = 0; ni < 4; ++ni) {
            int row = wn * 64 + ni * 16 + lr;
#pragma unroll
            for (int ks = 0; ks < 2; ++ks) {
                int kc = ks * 4 + q4;
                bf[ni][ks] = *(const u16x8*)(bb + row * 64 + (kc ^ (row & 7)) * 8);
            }
        }
#pragma unroll
        for (int mi = 0; mi < 4; ++mi)
#pragma unroll
            for (int ni = 0; ni < 4; ++ni) {
                acc[mi][ni] = mfma_bf16(af[mi][0], bf[ni][0], acc[mi][ni]);
                acc[mi][ni] = mfma_bf16(af[mi][1], bf[ni][1], acc[mi][ni]);
            }
        __syncthreads();
        cur ^= 1;
    }

    // ---- epilogue ----
    const int sec = blockIdx.y / 6;          // 0=Q 1=K 2=V
    const int dsec = n0 - sec * 768;         // col base within section
    const int bidx = m0 >> 10;
    const int prow = m0 & 1023;
    if (sec < 2) {
        // Q/K: stage [p][d] tile in LDS (+pos, rounded), then u16x8 coalesced stores
        u16* outp = sec ? Kb : Qb;
#pragma unroll
        for (int mi = 0; mi < 4; ++mi)
#pragma unroll
            for (int ni = 0; ni < 4; ++ni) {
                const int dl = wn * 64 + ni * 16 + lr;
                const int d = dsec + dl;
#pragma unroll
                for (int r = 0; r < 4; ++r) {
                    const int pl = wm * 64 + mi * 16 + q4 * 4 + r;
                    const int p = prow + pl;
                    sm.vt[pl][dl] = f2bf(acc[mi][ni][r] + pos[p * 768 + d]);
                }
            }
        __syncthreads();
#pragma unroll
        for (int it = 0; it < 8; ++it) {
            const int idx = it * 256 + tid;
            const int pl = idx >> 4, c8 = (idx & 15) * 8;
            u16x8 val = *(const u16x8*)(&sm.vt[pl][c8]);
            const int d = dsec + c8, h = d >> 6, hd = d & 63;
            *(u16x8*)(outp + (size_t)((bidx * 12 + h) * 1024 + prow + pl) * 64 + hd) = val;
        }
    } else {
        // V: transpose through LDS, write Vt[b,h,hd,p] coalesced
#pragma unroll
        for (int mi = 0; mi < 4; ++mi)
#pragma unroll
            for (int ni = 0; ni < 4; ++ni) {
                int col = wn * 64 + ni * 16 + lr;   // local d 0..127
                int d = dsec + col;
                u16x4 pk;
#pragma unroll
                for (int r = 0; r < 4; ++r) {
                    int p = prow + wm * 64 + mi * 16 + q4 * 4 + r;
                    pk[r] = f2bf(acc[mi][ni][r] + pos[p * 768 + d]);
                }
                *(u16x4*)(&sm.vt[col][wm * 64 + mi * 16 + q4 * 4]) = pk;
            }
        __syncthreads();
#pragma unroll
        for (int it = 0; it < 8; ++it) {
            int idx = it * 256 + tid;
            int dl = idx >> 4, c8 = (idx & 15) * 8;
            u16x8 val = *(const u16x8*)(&sm.vt[dl][c8]);
            int d = dsec + dl, h = d >> 6, hd = d & 63;
            *(u16x8*)(Vt + (size_t)((bidx * 12 + h) * 64 + hd) * 1024 + prow + c8) = val;
        }
    }
}

// ---------------- production attn (exact R6 body) ----------------
__global__ __launch_bounds__(256, 4) void k_attn(const u16* __restrict__ Qb, const u16* __restrict__ Kb,
                                                 const u16* __restrict__ Vt, float* __restrict__ Pout,
                                                 float* __restrict__ pooled) {
    __shared__ __align__(16) u16 P_lds[4][16][64];
    __shared__ float stats[16 * 4 * 2];
    const int tid = threadIdx.x;
    const int l = tid & 63, w = tid >> 6;
    const int lr = l & 15, q4 = l >> 4;
    const int bh = blockIdx.y, q0 = blockIdx.x * 16;
    const u16* Qh = Qb + (size_t)bh * 65536;
    const u16* Kh = Kb + (size_t)bh * 65536;
    const u16* Vh = Vt + (size_t)bh * 65536;

    u16x8 qf[2];
#pragma unroll
    for (int ks = 0; ks < 2; ++ks)
        qf[ks] = *(const u16x8*)(Qh + (size_t)(q0 + lr) * 64 + ks * 32 + q4 * 8);

    f32x4 acc[16];
#pragma unroll
    for (int nf = 0; nf < 16; ++nf) acc[nf] = (f32x4){0.f, 0.f, 0.f, 0.f};

    const int kc0 = w * 256;
#pragma unroll
    for (int nf = 0; nf < 16; ++nf) {
        const u16* kp = Kh + (size_t)(kc0 + nf * 16 + lr) * 64 + q4 * 8;
        u16x8 kf0 = *(const u16x8*)kp;
        u16x8 kf1 = *(const u16x8*)(kp + 32);
        acc[nf] = mfma_bf16(qf[0], kf0, acc[nf]);
        acc[nf] = mfma_bf16(qf[1], kf1, acc[nf]);
    }

    float mx[4], inv4[4];
#pragma unroll
    for (int r = 0; r < 4; ++r) {
        float m = acc[0][r];
#pragma unroll
        for (int nf = 1; nf < 16; ++nf) m = fmaxf(m, acc[nf][r]);
        m = fmaxf(m, __shfl_xor(m, 1));
        m = fmaxf(m, __shfl_xor(m, 2));
        m = fmaxf(m, __shfl_xor(m, 4));
        m = fmaxf(m, __shfl_xor(m, 8));
        if (lr == 0) stats[(q4 * 4 + r) * 4 + w] = m;
    }
    __syncthreads();
#pragma unroll
    for (int r = 0; r < 4; ++r) {
        f32x4 s4 = *(const f32x4*)(stats + (q4 * 4 + r) * 4);
        mx[r] = fmaxf(fmaxf(s4[0], s4[1]), fmaxf(s4[2], s4[3]));
    }

    const float cs = 0.125f * 1.44269504f;
#pragma unroll
    for (int r = 0; r < 4; ++r) {
        float s = 0.f;
#pragma unroll
        for (int nf = 0; nf < 16; ++nf) {
            float e = exp2f((acc[nf][r] - mx[r]) * cs);
            acc[nf][r] = e;
            s += e;
        }
        s += __shfl_xor(s, 1);
        s += __shfl_xor(s, 2);
        s += __shfl_xor(s, 4);
        s += __shfl_xor(s, 8);
        if (lr == 0) stats[64 + (q4 * 4 + r) * 4 + w] = s;
    }
    __syncthreads();
#pragma unroll
    for (int r = 0; r < 4; ++r) {
        f32x4 s4 = *(const f32x4*)(stats + 64 + (q4 * 4 + r) * 4);
        inv4[r] = 1.f / (s4[0] + s4[1] + s4[2] + s4[3]);
    }

    float* Pbase = Pout + ((size_t)bh * 1024 + q0) * 1024 + kc0;
    f32x4 acc2[4];
#pragma unroll
    for (int nd = 0; nd < 4; ++nd) acc2[nd] = (f32x4){0.f, 0.f, 0.f, 0.f};
    const int swa = (lr & 7) << 3;
    const int scol = lr * 4;

#pragma unroll
    for (int c = 0; c < 4; ++c) {
#pragma unroll
        for (int r = 0; r < 4; ++r) {
            const int row = q4 * 4 + r;
            const int sw = (row & 7) << 3;
            const float iv = inv4[r];
#pragma unroll
            for (int nfl = 0; nfl < 4; ++nfl) {
                const int nf = c * 4 + nfl;
                P_lds[w][row][(nfl * 16 + lr) ^ sw] = f2bf(acc[nf][r] * iv);
            }
        }
#pragma unroll
        for (int t = 0; t < 4; ++t) {
            const int row = t * 4 + q4;
            const int sw = (row & 7) << 3;
            u16x4 pb = *(const u16x4*)(&P_lds[w][row][scol ^ sw]);
            f32x4 pf = {bf2f(pb[0]), bf2f(pb[1]), bf2f(pb[2]), bf2f(pb[3])};
            __builtin_nontemporal_store(pf, (f32x4*)(Pbase + (size_t)row * 1024 + c * 64 + scol));
        }
        const u16* vb = Vh + kc0 + c * 64 + q4 * 8;
#pragma unroll
        for (int ks = 0; ks < 2; ++ks) {
            u16x8 a = *(const u16x8*)(&P_lds[w][lr][(ks * 32 + q4 * 8) ^ swa]);
#pragma unroll
            for (int nd = 0; nd < 4; ++nd) {
                u16x8 b = *(const u16x8*)(vb + (size_t)(nd * 16 + lr) * 1024 + ks * 32);
                acc2[nd] = mfma_bf16(a, b, acc2[nd]);
            }
        }
    }

    const int bb = bh / 12, hh = bh % 12;
#pragma unroll
    for (int nd = 0; nd < 4; ++nd) {
        float s = acc2[nd][0] + acc2[nd][1] + acc2[nd][2] + acc2[nd][3];
        s += __shfl_xor(s, 16);
        s += __shfl_xor(s, 32);
        if (l < 16) atomicAdd(pooled + bb * 768 + hh * 64 + nd * 16 + l, s);
    }
}

// ---------------- k_attnM: R6 body, doubled grid (counter probe) ----------------
__global__ __launch_bounds__(256, 4) void k_attnM(const u16* __restrict__ Qb, const u16* __restrict__ Kb,
                                                  const u16* __restrict__ Vt, float* __restrict__ Pout,
                                                  float* __restrict__ pooled) {
    __shared__ __align__(16) u16 P_lds[4][16][64];
    __shared__ float stats[16 * 4 * 2];
    const int tid = threadIdx.x;
    const int l = tid & 63, w = tid >> 6;
    const int lr = l & 15, q4 = l >> 4;
    const int bhy = blockIdx.y;
    const int bh = bhy >= 192 ? bhy - 192 : bhy;
    const int q0 = blockIdx.x * 16;
    const u16* Qh = Qb + (size_t)bh * 65536;
    const u16* Kh = Kb + (size_t)bh * 65536;
    const u16* Vh = Vt + (size_t)bh * 65536;

    u16x8 qf[2];
#pragma unroll
    for (int ks = 0; ks < 2; ++ks)
        qf[ks] = *(const u16x8*)(Qh + (size_t)(q0 + lr) * 64 + ks * 32 + q4 * 8);

    f32x4 acc[16];
#pragma unroll
    for (int nf = 0; nf < 16; ++nf) acc[nf] = (f32x4){0.f, 0.f, 0.f, 0.f};

    const int kc0 = w * 256;
#pragma unroll
    for (int nf = 0; nf < 16; ++nf) {
        const u16* kp = Kh + (size_t)(kc0 + nf * 16 + lr) * 64 + q4 * 8;
        u16x8 kf0 = *(const u16x8*)kp;
        u16x8 kf1 = *(const u16x8*)(kp + 32);
        acc[nf] = mfma_bf16(qf[0], kf0, acc[nf]);
        acc[nf] = mfma_bf16(qf[1], kf1, acc[nf]);
    }

    float mx[4], inv4[4];
#pragma unroll
    for (int r = 0; r < 4; ++r) {
        float m = acc[0][r];
#pragma unroll
        for (int nf = 1; nf < 16; ++nf) m = fmaxf(m, acc[nf][r]);
        m = fmaxf(m, __shfl_xor(m, 1));
        m = fmaxf(m, __shfl_xor(m, 2));
        m = fmaxf(m, __shfl_xor(m, 4));
        m = fmaxf(m, __shfl_xor(m, 8));
        if (lr == 0) stats[(q4 * 4 + r) * 4 + w] = m;
    }
    __syncthreads();
#pragma unroll
    for (int r = 0; r < 4; ++r) {
        f32x4 s4 = *(const f32x4*)(stats + (q4 * 4 + r) * 4);
        mx[r] = fmaxf(fmaxf(s4[0], s4[1]), fmaxf(s4[2], s4[3]));
    }

    const float cs = 0.125f * 1.44269504f;
#pragma unroll
    for (int r = 0; r < 4; ++r) {
        float s = 0.f;
#pragma unroll
        for (int nf = 0; nf < 16; ++nf) {
            float e = exp2f((acc[nf][r] - mx[r]) * cs);
            acc[nf][r] = e;
            s += e;
        }
        s += __shfl_xor(s, 1);
        s += __shfl_xor(s, 2);
        s += __shfl_xor(s, 4);
        s += __shfl_xor(s, 8);
        if (lr == 0) stats[64 + (q4 * 4 + r) * 4 + w] = s;
    }
    __syncthreads();
#pragma unroll
    for (int r = 0; r < 4; ++r) {
        f32x4 s4 = *(const f32x4*)(stats + 64 + (q4 * 4 + r) * 4);
        inv4[r] = 1.f / (s4[0] + s4[1] + s4[2] + s4[3]);
    }

    float* Pbase = Pout + ((size_t)bh * 1024 + q0) * 1024 + kc0;
    f32x4 acc2[4];
#pragma unroll
    for (int nd = 0; nd < 4; ++nd) acc2[nd] = (f32x4){0.f, 0.f, 0.f, 0.f};
    const int swa = (lr & 7) << 3;
    const int scol = lr * 4;

#pragma unroll
    for (int c = 0; c < 4; ++c) {
#pragma unroll
        for (int r = 0; r < 4; ++r) {
            const int row = q4 * 4 + r;
            const int sw = (row & 7) << 3;
            const float iv = inv4[r];
#pragma unroll
            for (int nfl = 0; nfl < 4; ++nfl) {
                const int nf = c * 4 + nfl;
                P_lds[w][row][(nfl * 16 + lr) ^ sw] = f2bf(acc[nf][r] * iv);
            }
        }
#pragma unroll
        for (int t = 0; t < 4; ++t) {
            const int row = t * 4 + q4;
            const int sw = (row & 7) << 3;
            u16x4 pb = *(const u16x4*)(&P_lds[w][row][scol ^ sw]);
            f32x4 pf = {bf2f(pb[0]), bf2f(pb[1]), bf2f(pb[2]), bf2f(pb[3])};
            __builtin_nontemporal_store(pf, (f32x4*)(Pbase + (size_t)row * 1024 + c * 64 + scol));
        }
        const u16* vb = Vh + kc0 + c * 64 + q4 * 8;
#pragma unroll
        for (int ks = 0; ks < 2; ++ks) {
            u16x8 a = *(const u16x8*)(&P_lds[w][lr][(ks * 32 + q4 * 8) ^ swa]);
#pragma unroll
            for (int nd = 0; nd < 4; ++nd) {
                u16x8 b = *(const u16x8*)(vb + (size_t)(nd * 16 + lr) * 1024 + ks * 32);
                acc2[nd] = mfma_bf16(a, b, acc2[nd]);
            }
        }
    }

    const int bb = bh / 12, hh = bh % 12;
#pragma unroll
    for (int nd = 0; nd < 4; ++nd) {
        float s = acc2[nd][0] + acc2[nd][1] + acc2[nd][2] + acc2[nd][3];
        s += __shfl_xor(s, 16);
        s += __shfl_xor(s, 32);
        if (l < 16) atomicAdd(pooled + bb * 768 + hh * 64 + nd * 16 + l, s);
    }
}

// ---------------- k_attnF: candidate — no-max softmax, asm exp, direct reg stores ----------------
__global__ __launch_bounds__(256, 4) void k_attnF(const u16* __restrict__ Qb, const u16* __restrict__ Kb,
                                                  const u16* __restrict__ Vt, float* __restrict__ Pout,
                                                  float* __restrict__ pooled) {
    __shared__ __align__(16) u16 P_lds[4][16][256];  // full-width PV strip, 32KB
    __shared__ float stats[64];                      // sum only
    const int tid = threadIdx.x;
    const int l = tid & 63, w = tid >> 6;
    const int lr = l & 15, q4 = l >> 4;
    const int bhy = blockIdx.y;
    const int bh = bhy >= 192 ? bhy - 192 : bhy;
    const int q0 = blockIdx.x * 16;
    const u16* Qh = Qb + (size_t)bh * 65536;
    const u16* Kh = Kb + (size_t)bh * 65536;
    const u16* Vh = Vt + (size_t)bh * 65536;

    u16x8 qf[2];
#pragma unroll
    for (int ks = 0; ks < 2; ++ks)
        qf[ks] = *(const u16x8*)(Qh + (size_t)(q0 + lr) * 64 + ks * 32 + q4 * 8);

    f32x4 acc[16];
#pragma unroll
    for (int nf = 0; nf < 16; ++nf) acc[nf] = (f32x4){0.f, 0.f, 0.f, 0.f};

    const int kc0 = w * 256;
#pragma unroll
    for (int nf = 0; nf < 16; ++nf) {
        const u16* kp = Kh + (size_t)(kc0 + nf * 16 + lr) * 64 + q4 * 8;
        u16x8 kf0 = *(const u16x8*)kp;
        u16x8 kf1 = *(const u16x8*)(kp + 32);
        acc[nf] = mfma_bf16(qf[0], kf0, acc[nf]);
        acc[nf] = mfma_bf16(qf[1], kf1, acc[nf]);
    }

    // exp without max subtraction (scores |s|<~3; overflow needs s~700)
    const float cs = 0.125f * 1.44269504f;
    float inv4[4];
#pragma unroll
    for (int r = 0; r < 4; ++r) {
        float s = 0.f;
#pragma unroll
        for (int nf = 0; nf < 16; ++nf) {
            float e = fast_exp2(acc[nf][r] * cs);
            acc[nf][r] = e;
            s += e;
        }
        s += __shfl_xor(s, 1);
        s += __shfl_xor(s, 2);
        s += __shfl_xor(s, 4);
        s += __shfl_xor(s, 8);
        if (lr == 0) stats[(q4 * 4 + r) * 4 + w] = s;
    }
    __syncthreads();
#pragma unroll
    for (int r = 0; r < 4; ++r) {
        f32x4 s4 = *(const f32x4*)(stats + (q4 * 4 + r) * 4);
        inv4[r] = 1.f / (s4[0] + s4[1] + s4[2] + s4[3]);
    }

    // normalize -> direct scalar nt f32 stores + full-width bf16 strip
    float* Prow = Pout + ((size_t)bh * 1024 + q0) * 1024 + kc0;
#pragma unroll
    for (int c = 0; c < 4; ++c)
#pragma unroll
        for (int r = 0; r < 4; ++r) {
            const int row = q4 * 4 + r;
            const int sw = (row & 7) << 3;
            const float iv = inv4[r];
#pragma unroll
            for (int nfl = 0; nfl < 4; ++nfl) {
                const int nf = c * 4 + nfl;
                float p = acc[nf][r] * iv;
                __builtin_nontemporal_store(p, &Prow[(size_t)row * 1024 + nf * 16 + lr]);
                P_lds[w][row][c * 64 + ((nfl * 16 + lr) ^ sw)] = f2bf(p);
            }
        }

    // PV over full strip (wave-private)
    f32x4 acc2[4];
#pragma unroll
    for (int nd = 0; nd < 4; ++nd) acc2[nd] = (f32x4){0.f, 0.f, 0.f, 0.f};
    const int swa = (lr & 7) << 3;
#pragma unroll
    for (int c = 0; c < 4; ++c) {
        const u16* vb = Vh + kc0 + c * 64 + q4 * 8;
#pragma unroll
        for (int ks = 0; ks < 2; ++ks) {
            u16x8 a = *(const u16x8*)(&P_lds[w][lr][c * 64 + ((ks * 32 + q4 * 8) ^ swa)]);
#pragma unroll
            for (int nd = 0; nd < 4; ++nd) {
                u16x8 b = *(const u16x8*)(vb + (size_t)(nd * 16 + lr) * 1024 + ks * 32);
                acc2[nd] = mfma_bf16(a, b, acc2[nd]);
            }
        }
    }

    const int bb = bh / 12, hh = bh % 12;
#pragma unroll
    for (int nd = 0; nd < 4; ++nd) {
        float s = acc2[nd][0] + acc2[nd][1] + acc2[nd][2] + acc2[nd][3];
        s += __shfl_xor(s, 16);
        s += __shfl_xor(s, 32);
        if (l < 16) atomicAdd(pooled + bb * 768 + hh * 64 + nd * 16 + l, s);
    }
}

// ---------------- pooled/1024 @ Wo + bo -> tmp[16,768] ----------------
__global__ __launch_bounds__(128) void k_proj(const float* __restrict__ pooled_sum,
                                              const float* __restrict__ Wo, const float* __restrict__ bo,
                                              float* __restrict__ tmp) {
    const int b = blockIdx.y, j = blockIdx.x * 128 + threadIdx.x;
    __shared__ float pr[768];
    for (int i = threadIdx.x; i < 768; i += 128) pr[i] = pooled_sum[b * 768 + i] * (1.0f / 1024.0f);
    __syncthreads();
    float s = bo[j];
#pragma unroll 4
    for (int d = 0; d < 768; ++d) s = fmaf(pr[d], Wo[d * 768 + j], s);
    tmp[b * 768 + j] = s;
}

// ---------------- tmp @ Wc + bc -> logits ----------------
__global__ __launch_bounds__(128) void k_cls(const float* __restrict__ tmp,
                                             const float* __restrict__ Wc, const float* __restrict__ bc,
                                             float* __restrict__ out) {
    const int b = blockIdx.y, c = blockIdx.x * 128 + threadIdx.x;
    __shared__ float tr[768];
    for (int i = threadIdx.x; i < 768; i += 128) tr[i] = tmp[b * 768 + i];
    __syncthreads();
    if (c >= 1000) return;
    float s = bc[c];
#pragma unroll 4
    for (int j = 0; j < 768; ++j) s = fmaf(tr[j], Wc[j * 1000 + c], s);
    out[b * 1000 + c] = s;
}

extern "C" void kernel_launch(void* const* d_in, const int* in_sizes, int n_in,
                              void* d_out, int out_size, void* d_ws, size_t ws_size,
                              hipStream_t stream) {
    const float* x    = (const float*)d_in[0];
    const float* Wqkv = (const float*)d_in[1];
    const float* pos  = (const float*)d_in[2];
    const float* Wo   = (const float*)d_in[3];
    const float* bo   = (const float*)d_in[4];
    const float* Wc   = (const float*)d_in[5];
    const float* bc   = (const float*)d_in[6];
    float* out  = (float*)d_out;
    float* attn = out + 16000;  // logits [16,1000] first, then attn_weights [16,12,1024,1024]

    char* ws = (char*)d_ws;
    u16* xb = (u16*)ws;  ws += (size_t)16384 * 768 * 2;
    u16* Wt = (u16*)ws;  ws += (size_t)2304 * 768 * 2;
    u16* Qb = (u16*)ws;  ws += (size_t)192 * 1024 * 64 * 2;
    u16* Kb = (u16*)ws;  ws += (size_t)192 * 1024 * 64 * 2;
    u16* Vt = (u16*)ws;  ws += (size_t)192 * 1024 * 64 * 2;
    float* pooled = (float*)ws;  ws += 16 * 768 * sizeof(float);
    float* tmp = (float*)ws;

    // MEASUREMENT: doubled-grid attn probes F and M (>500us each -> counters
    // visible). Production pass runs LAST with fresh pooled; outputs exact.
    k_cast_x<<<6144, 256, 0, stream>>>(x, xb);
    k_transpose_w<<<dim3(36, 12), 256, 0, stream>>>(Wqkv, Wt);
    k_qkv<<<dim3(128, 18), 256, 0, stream>>>(xb, Wt, pos, Qb, Kb, Vt);
    k_attnF<<<dim3(64, 384), 256, 0, stream>>>(Qb, Kb, Vt, attn, pooled);
    k_attnM<<<dim3(64, 384), 256, 0, stream>>>(Qb, Kb, Vt, attn, pooled);
    hipMemsetAsync(pooled, 0, 16 * 768 * sizeof(float), stream);
    k_attn<<<dim3(64, 192), 256, 0, stream>>>(Qb, Kb, Vt, attn, pooled);
    k_proj<<<dim3(6, 16), 128, 0, stream>>>(pooled, Wo, bo, tmp);
    k_cls<<<dim3(8, 16), 128, 0, stream>>>(tmp, Wc, bc, out);
}

// Round 12
// 591.708 us; speedup vs baseline: 16.3060x; 3.6316x over previous
//
#include <hip/hip_runtime.h>

#define DI __device__ __forceinline__

typedef float f32x4 __attribute__((ext_vector_type(4)));
typedef unsigned short u16;
typedef u16 u16x8 __attribute__((ext_vector_type(8)));
typedef u16 u16x4 __attribute__((ext_vector_type(4)));
typedef __bf16 bf16x8 __attribute__((ext_vector_type(8)));

DI u16 f2bf(float f) {
    unsigned u = __builtin_bit_cast(unsigned, f);
    u += 0x7fffu + ((u >> 16) & 1u);
    return (u16)(u >> 16);
}

DI float bf2f(u16 b) {
    unsigned u = ((unsigned)b) << 16;
    return __builtin_bit_cast(float, u);
}

DI f32x4 mfma_bf16(u16x8 a, u16x8 b, f32x4 c) {
    return __builtin_amdgcn_mfma_f32_16x16x32_bf16(
        __builtin_bit_cast(bf16x8, a), __builtin_bit_cast(bf16x8, b), c, 0, 0, 0);
}

DI void gload_lds16(const void* g, void* l) {
    __builtin_amdgcn_global_load_lds(
        (const __attribute__((address_space(1))) unsigned int*)g,
        (__attribute__((address_space(3))) unsigned int*)l, 16, 0, 0);
}

DI float fast_exp2(float x) {
    float e;
    asm("v_exp_f32 %0, %1" : "=v"(e) : "v"(x));
    return e;
}

// ---------------- cast x -> bf16 ----------------
__global__ __launch_bounds__(256) void k_cast_x(const float* __restrict__ x, u16* __restrict__ xb) {
    size_t i = (size_t)blockIdx.x * 256 + threadIdx.x;  // 8 elems each
    const f32x4* p = (const f32x4*)(x + i * 8);
    f32x4 a = p[0], b = p[1];
    u16x8 o;
    o[0] = f2bf(a[0]); o[1] = f2bf(a[1]); o[2] = f2bf(a[2]); o[3] = f2bf(a[3]);
    o[4] = f2bf(b[0]); o[5] = f2bf(b[1]); o[6] = f2bf(b[2]); o[7] = f2bf(b[3]);
    *(u16x8*)(xb + i * 8) = o;
}

// ---------------- transpose Wqkv [768,2304] -> Wt bf16 [2304,768] ----------------
__global__ __launch_bounds__(256) void k_transpose_w(const float* __restrict__ W, u16* __restrict__ Wt) {
    __shared__ float tile[64][65];
    const int t = threadIdx.x;
    const int nb = blockIdx.x * 64, kb = blockIdx.y * 64;
#pragma unroll
    for (int it = 0; it < 4; ++it) {
        int idx = it * 256 + t;
        int kl = idx >> 4, nl4 = (idx & 15) * 4;
        f32x4 v = *(const f32x4*)(W + (size_t)(kb + kl) * 2304 + nb + nl4);
        tile[kl][nl4 + 0] = v[0]; tile[kl][nl4 + 1] = v[1];
        tile[kl][nl4 + 2] = v[2]; tile[kl][nl4 + 3] = v[3];
    }
    __syncthreads();
#pragma unroll
    for (int it = 0; it < 2; ++it) {
        int idx = it * 256 + t;
        int nl = idx >> 3, kc = (idx & 7) * 8;
        u16x8 o;
#pragma unroll
        for (int j = 0; j < 8; ++j) o[j] = f2bf(tile[kc + j][nl]);
        *(u16x8*)(Wt + (size_t)(nb + nl) * 768 + kb + kc) = o;
    }
}

// ---------------- QKV GEMM: xb[16384,768] @ Wt^T -> Q,K [B,H,P,64], Vt [B,H,64,P] ----------------
__global__ __launch_bounds__(256, 2) void k_qkv(const u16* __restrict__ A, const u16* __restrict__ Bt,
                                                const float* __restrict__ pos, u16* __restrict__ Qb,
                                                u16* __restrict__ Kb, u16* __restrict__ Vt) {
    __shared__ __align__(16) union SM {
        u16 stage[2][2][8192];  // [buf][A/B][128 rows x 64 k]
        u16 vt[128][136];       // epilogue transpose tile (rows 16B-aligned: 272B)
    } sm;
    const int tid = threadIdx.x;
    const int l = tid & 63, w = tid >> 6;
    const int wm = w >> 1, wn = w & 1;
    const int m0 = blockIdx.x * 128, n0 = blockIdx.y * 128;
    const int srow = l >> 3, sslot = (l & 7) ^ srow;
    const int q4 = l >> 4, lr = l & 15;

    f32x4 acc[4][4];
#pragma unroll
    for (int i = 0; i < 4; ++i)
#pragma unroll
        for (int j = 0; j < 4; ++j) acc[i][j] = (f32x4){0.f, 0.f, 0.f, 0.f};

    const size_t abase = (size_t)(m0 + srow) * 768 + sslot * 8;
    const size_t bbase = (size_t)(n0 + srow) * 768 + sslot * 8;

    // prologue stage kt=0
#pragma unroll
    for (int i = 0; i < 4; ++i) {
        int chunk = w * 4 + i;
        gload_lds16(A + abase + (size_t)chunk * 8 * 768, &sm.stage[0][0][chunk * 512]);
        gload_lds16(Bt + bbase + (size_t)chunk * 8 * 768, &sm.stage[0][1][chunk * 512]);
    }
    __syncthreads();

    int cur = 0;
    for (int kt = 0; kt < 12; ++kt) {
        if (kt < 11) {
            const size_t ko = (size_t)(kt + 1) * 64;
#pragma unroll
            for (int i = 0; i < 4; ++i) {
                int chunk = w * 4 + i;
                gload_lds16(A + abase + (size_t)chunk * 8 * 768 + ko, &sm.stage[cur ^ 1][0][chunk * 512]);
                gload_lds16(Bt + bbase + (size_t)chunk * 8 * 768 + ko, &sm.stage[cur ^ 1][1][chunk * 512]);
            }
        }
        const u16* ab = sm.stage[cur][0];
        const u16* bb = sm.stage[cur][1];
        u16x8 af[4][2], bf[4][2];
#pragma unroll
        for (int mi = 0; mi < 4; ++mi) {
            int row = wm * 64 + mi * 16 + lr;
#pragma unroll
            for (int ks = 0; ks < 2; ++ks) {
                int kc = ks * 4 + q4;
                af[mi][ks] = *(const u16x8*)(ab + row * 64 + (kc ^ (row & 7)) * 8);
            }
        }
#pragma unroll
        for (int ni = 0; ni < 4; ++ni) {
            int row = wn * 64 + ni * 16 + lr;
#pragma unroll
            for (int ks = 0; ks < 2; ++ks) {
                int kc = ks * 4 + q4;
                bf[ni][ks] = *(const u16x8*)(bb + row * 64 + (kc ^ (row & 7)) * 8);
            }
        }
#pragma unroll
        for (int mi = 0; mi < 4; ++mi)
#pragma unroll
            for (int ni = 0; ni < 4; ++ni) {
                acc[mi][ni] = mfma_bf16(af[mi][0], bf[ni][0], acc[mi][ni]);
                acc[mi][ni] = mfma_bf16(af[mi][1], bf[ni][1], acc[mi][ni]);
            }
        __syncthreads();
        cur ^= 1;
    }

    // ---- epilogue ----
    const int sec = blockIdx.y / 6;          // 0=Q 1=K 2=V
    const int dsec = n0 - sec * 768;         // col base within section
    const int bidx = m0 >> 10;
    const int prow = m0 & 1023;
    if (sec < 2) {
        // Q/K: stage [p][d] tile in LDS (+pos, rounded), then u16x8 coalesced stores
        u16* outp = sec ? Kb : Qb;
#pragma unroll
        for (int mi = 0; mi < 4; ++mi)
#pragma unroll
            for (int ni = 0; ni < 4; ++ni) {
                const int dl = wn * 64 + ni * 16 + lr;
                const int d = dsec + dl;
#pragma unroll
                for (int r = 0; r < 4; ++r) {
                    const int pl = wm * 64 + mi * 16 + q4 * 4 + r;
                    const int p = prow + pl;
                    sm.vt[pl][dl] = f2bf(acc[mi][ni][r] + pos[p * 768 + d]);
                }
            }
        __syncthreads();
#pragma unroll
        for (int it = 0; it < 8; ++it) {
            const int idx = it * 256 + tid;
            const int pl = idx >> 4, c8 = (idx & 15) * 8;
            u16x8 val = *(const u16x8*)(&sm.vt[pl][c8]);
            const int d = dsec + c8, h = d >> 6, hd = d & 63;
            *(u16x8*)(outp + (size_t)((bidx * 12 + h) * 1024 + prow + pl) * 64 + hd) = val;
        }
    } else {
        // V: transpose through LDS, write Vt[b,h,hd,p] coalesced
#pragma unroll
        for (int mi = 0; mi < 4; ++mi)
#pragma unroll
            for (int ni = 0; ni < 4; ++ni) {
                int col = wn * 64 + ni * 16 + lr;   // local d 0..127
                int d = dsec + col;
                u16x4 pk;
#pragma unroll
                for (int r = 0; r < 4; ++r) {
                    int p = prow + wm * 64 + mi * 16 + q4 * 4 + r;
                    pk[r] = f2bf(acc[mi][ni][r] + pos[p * 768 + d]);
                }
                *(u16x4*)(&sm.vt[col][wm * 64 + mi * 16 + q4 * 4]) = pk;
            }
        __syncthreads();
#pragma unroll
        for (int it = 0; it < 8; ++it) {
            int idx = it * 256 + tid;
            int dl = idx >> 4, c8 = (idx & 15) * 8;
            u16x8 val = *(const u16x8*)(&sm.vt[dl][c8]);
            int d = dsec + dl, h = d >> 6, hd = d & 63;
            *(u16x8*)(Vt + (size_t)((bidx * 12 + h) * 64 + hd) * 1024 + prow + c8) = val;
        }
    }
}

// ---------------- fused attention: no-max softmax, block-reduced pooled atomics ----------------
__global__ __launch_bounds__(256, 4) void k_attn(const u16* __restrict__ Qb, const u16* __restrict__ Kb,
                                                 const u16* __restrict__ Vt, float* __restrict__ Pout,
                                                 float* __restrict__ pooled) {
    __shared__ __align__(16) u16 P_lds[4][16][64];   // 8KB wave-private chunk strips
    __shared__ float stats[64];                      // row sums [row16*4 + wave]
    __shared__ float psum[4][64];                    // per-wave pooled partials
    const int tid = threadIdx.x;
    const int l = tid & 63, w = tid >> 6;
    const int lr = l & 15, q4 = l >> 4;
    const int bh = blockIdx.y, q0 = blockIdx.x * 16;
    const u16* Qh = Qb + (size_t)bh * 65536;
    const u16* Kh = Kb + (size_t)bh * 65536;
    const u16* Vh = Vt + (size_t)bh * 65536;

    u16x8 qf[2];
#pragma unroll
    for (int ks = 0; ks < 2; ++ks)
        qf[ks] = *(const u16x8*)(Qh + (size_t)(q0 + lr) * 64 + ks * 32 + q4 * 8);

    f32x4 acc[16];
#pragma unroll
    for (int nf = 0; nf < 16; ++nf) acc[nf] = (f32x4){0.f, 0.f, 0.f, 0.f};

    const int kc0 = w * 256;
#pragma unroll
    for (int nf = 0; nf < 16; ++nf) {
        const u16* kp = Kh + (size_t)(kc0 + nf * 16 + lr) * 64 + q4 * 8;
        u16x8 kf0 = *(const u16x8*)kp;
        u16x8 kf1 = *(const u16x8*)(kp + 32);
        acc[nf] = mfma_bf16(qf[0], kf0, acc[nf]);
        acc[nf] = mfma_bf16(qf[1], kf1, acc[nf]);
    }

    // exp + row sum, no max subtraction (scores |s|<~4; exp2 range safe).
    // exp(s)/sum(exp(s)) is mathematically identical to max-subtracted softmax.
    const float cs = 0.125f * 1.44269504f;
    float inv4[4];
#pragma unroll
    for (int r = 0; r < 4; ++r) {
        float s = 0.f;
#pragma unroll
        for (int nf = 0; nf < 16; ++nf) {
            float e = fast_exp2(acc[nf][r] * cs);
            acc[nf][r] = e;
            s += e;
        }
        s += __shfl_xor(s, 1);
        s += __shfl_xor(s, 2);
        s += __shfl_xor(s, 4);
        s += __shfl_xor(s, 8);
        if (lr == 0) stats[(q4 * 4 + r) * 4 + w] = s;
    }
    __syncthreads();
#pragma unroll
    for (int r = 0; r < 4; ++r) {
        f32x4 s4 = *(const f32x4*)(stats + (q4 * 4 + r) * 4);
        inv4[r] = 1.f / (s4[0] + s4[1] + s4[2] + s4[3]);
    }

    // chunked (64 keys/chunk): normalize -> bf16 LDS strip (wave-private)
    //   -> f32x4 full-line nt stores -> PV
    float* Pbase = Pout + ((size_t)bh * 1024 + q0) * 1024 + kc0;
    f32x4 acc2[4];
#pragma unroll
    for (int nd = 0; nd < 4; ++nd) acc2[nd] = (f32x4){0.f, 0.f, 0.f, 0.f};
    const int swa = (lr & 7) << 3;
    const int scol = lr * 4;

#pragma unroll
    for (int c = 0; c < 4; ++c) {
#pragma unroll
        for (int r = 0; r < 4; ++r) {
            const int row = q4 * 4 + r;
            const int sw = (row & 7) << 3;
            const float iv = inv4[r];
#pragma unroll
            for (int nfl = 0; nfl < 4; ++nfl) {
                const int nf = c * 4 + nfl;
                P_lds[w][row][(nfl * 16 + lr) ^ sw] = f2bf(acc[nf][r] * iv);
            }
        }
#pragma unroll
        for (int t = 0; t < 4; ++t) {
            const int row = t * 4 + q4;
            const int sw = (row & 7) << 3;
            u16x4 pb = *(const u16x4*)(&P_lds[w][row][scol ^ sw]);
            f32x4 pf = {bf2f(pb[0]), bf2f(pb[1]), bf2f(pb[2]), bf2f(pb[3])};
            __builtin_nontemporal_store(pf, (f32x4*)(Pbase + (size_t)row * 1024 + c * 64 + scol));
        }
        const u16* vb = Vh + kc0 + c * 64 + q4 * 8;
#pragma unroll
        for (int ks = 0; ks < 2; ++ks) {
            u16x8 a = *(const u16x8*)(&P_lds[w][lr][(ks * 32 + q4 * 8) ^ swa]);
#pragma unroll
            for (int nd = 0; nd < 4; ++nd) {
                u16x8 b = *(const u16x8*)(vb + (size_t)(nd * 16 + lr) * 1024 + ks * 32);
                acc2[nd] = mfma_bf16(a, b, acc2[nd]);
            }
        }
    }

    // pooled tail: per-wave partials -> LDS -> single-wave, 64 atomics/block
    // (was 256 atomics/block with 4-way same-address concurrency)
#pragma unroll
    for (int nd = 0; nd < 4; ++nd) {
        float s = acc2[nd][0] + acc2[nd][1] + acc2[nd][2] + acc2[nd][3];
        s += __shfl_xor(s, 16);
        s += __shfl_xor(s, 32);
        if (l < 16) psum[w][nd * 16 + l] = s;
    }
    __syncthreads();
    if (w == 0) {
        const int bb = bh / 12, hh = bh % 12;
        float t = psum[0][l] + psum[1][l] + psum[2][l] + psum[3][l];
        atomicAdd(pooled + bb * 768 + hh * 64 + l, t);
    }
}

// ---------------- pooled/1024 @ Wo + bo -> tmp[16,768] ----------------
__global__ __launch_bounds__(128) void k_proj(const float* __restrict__ pooled_sum,
                                              const float* __restrict__ Wo, const float* __restrict__ bo,
                                              float* __restrict__ tmp) {
    const int b = blockIdx.y, j = blockIdx.x * 128 + threadIdx.x;
    __shared__ float pr[768];
    for (int i = threadIdx.x; i < 768; i += 128) pr[i] = pooled_sum[b * 768 + i] * (1.0f / 1024.0f);
    __syncthreads();
    float s = bo[j];
#pragma unroll 4
    for (int d = 0; d < 768; ++d) s = fmaf(pr[d], Wo[d * 768 + j], s);
    tmp[b * 768 + j] = s;
}

// ---------------- tmp @ Wc + bc -> logits ----------------
__global__ __launch_bounds__(128) void k_cls(const float* __restrict__ tmp,
                                             const float* __restrict__ Wc, const float* __restrict__ bc,
                                             float* __restrict__ out) {
    const int b = blockIdx.y, c = blockIdx.x * 128 + threadIdx.x;
    __shared__ float tr[768];
    for (int i = threadIdx.x; i < 768; i += 128) tr[i] = tmp[b * 768 + i];
    __syncthreads();
    if (c >= 1000) return;
    float s = bc[c];
#pragma unroll 4
    for (int j = 0; j < 768; ++j) s = fmaf(tr[j], Wc[j * 1000 + c], s);
    out[b * 1000 + c] = s;
}

extern "C" void kernel_launch(void* const* d_in, const int* in_sizes, int n_in,
                              void* d_out, int out_size, void* d_ws, size_t ws_size,
                              hipStream_t stream) {
    const float* x    = (const float*)d_in[0];
    const float* Wqkv = (const float*)d_in[1];
    const float* pos  = (const float*)d_in[2];
    const float* Wo   = (const float*)d_in[3];
    const float* bo   = (const float*)d_in[4];
    const float* Wc   = (const float*)d_in[5];
    const float* bc   = (const float*)d_in[6];
    float* out  = (float*)d_out;
    float* attn = out + 16000;  // logits [16,1000] first, then attn_weights [16,12,1024,1024]

    char* ws = (char*)d_ws;
    u16* xb = (u16*)ws;  ws += (size_t)16384 * 768 * 2;
    u16* Wt = (u16*)ws;  ws += (size_t)2304 * 768 * 2;
    u16* Qb = (u16*)ws;  ws += (size_t)192 * 1024 * 64 * 2;
    u16* Kb = (u16*)ws;  ws += (size_t)192 * 1024 * 64 * 2;
    u16* Vt = (u16*)ws;  ws += (size_t)192 * 1024 * 64 * 2;
    float* pooled = (float*)ws;  ws += 16 * 768 * sizeof(float);
    float* tmp = (float*)ws;

    hipMemsetAsync(pooled, 0, 16 * 768 * sizeof(float), stream);
    k_cast_x<<<6144, 256, 0, stream>>>(x, xb);
    k_transpose_w<<<dim3(36, 12), 256, 0, stream>>>(Wqkv, Wt);
    k_qkv<<<dim3(128, 18), 256, 0, stream>>>(xb, Wt, pos, Qb, Kb, Vt);
    k_attn<<<dim3(64, 192), 256, 0, stream>>>(Qb, Kb, Vt, attn, pooled);
    k_proj<<<dim3(6, 16), 128, 0, stream>>>(pooled, Wo, bo, tmp);
    k_cls<<<dim3(8, 16), 128, 0, stream>>>(tmp, Wc, bc, out);
}

// Round 13
// 447.529 us; speedup vs baseline: 21.5593x; 1.3222x over previous
//
#include <hip/hip_runtime.h>

#define DI __device__ __forceinline__

typedef float f32x4 __attribute__((ext_vector_type(4)));
typedef unsigned short u16;
typedef u16 u16x8 __attribute__((ext_vector_type(8)));
typedef u16 u16x4 __attribute__((ext_vector_type(4)));
typedef __bf16 bf16x8 __attribute__((ext_vector_type(8)));

DI u16 f2bf(float f) {
    unsigned u = __builtin_bit_cast(unsigned, f);
    u += 0x7fffu + ((u >> 16) & 1u);
    return (u16)(u >> 16);
}

DI float bf2f(u16 b) {
    unsigned u = ((unsigned)b) << 16;
    return __builtin_bit_cast(float, u);
}

DI f32x4 mfma_bf16(u16x8 a, u16x8 b, f32x4 c) {
    return __builtin_amdgcn_mfma_f32_16x16x32_bf16(
        __builtin_bit_cast(bf16x8, a), __builtin_bit_cast(bf16x8, b), c, 0, 0, 0);
}

DI void gload_lds16(const void* g, void* l) {
    __builtin_amdgcn_global_load_lds(
        (const __attribute__((address_space(1))) unsigned int*)g,
        (__attribute__((address_space(3))) unsigned int*)l, 16, 0, 0);
}

DI float fast_exp2(float x) {
    float e;
    asm("v_exp_f32 %0, %1" : "=v"(e) : "v"(x));
    return e;
}

// ---------------- cast x -> bf16 ----------------
__global__ __launch_bounds__(256) void k_cast_x(const float* __restrict__ x, u16* __restrict__ xb) {
    size_t i = (size_t)blockIdx.x * 256 + threadIdx.x;  // 8 elems each
    const f32x4* p = (const f32x4*)(x + i * 8);
    f32x4 a = p[0], b = p[1];
    u16x8 o;
    o[0] = f2bf(a[0]); o[1] = f2bf(a[1]); o[2] = f2bf(a[2]); o[3] = f2bf(a[3]);
    o[4] = f2bf(b[0]); o[5] = f2bf(b[1]); o[6] = f2bf(b[2]); o[7] = f2bf(b[3]);
    *(u16x8*)(xb + i * 8) = o;
}

// ---------------- transpose Wqkv [768,2304] -> Wt bf16 [2304,768] ----------------
__global__ __launch_bounds__(256) void k_transpose_w(const float* __restrict__ W, u16* __restrict__ Wt) {
    __shared__ float tile[64][65];
    const int t = threadIdx.x;
    const int nb = blockIdx.x * 64, kb = blockIdx.y * 64;
#pragma unroll
    for (int it = 0; it < 4; ++it) {
        int idx = it * 256 + t;
        int kl = idx >> 4, nl4 = (idx & 15) * 4;
        f32x4 v = *(const f32x4*)(W + (size_t)(kb + kl) * 2304 + nb + nl4);
        tile[kl][nl4 + 0] = v[0]; tile[kl][nl4 + 1] = v[1];
        tile[kl][nl4 + 2] = v[2]; tile[kl][nl4 + 3] = v[3];
    }
    __syncthreads();
#pragma unroll
    for (int it = 0; it < 2; ++it) {
        int idx = it * 256 + t;
        int nl = idx >> 3, kc = (idx & 7) * 8;
        u16x8 o;
#pragma unroll
        for (int j = 0; j < 8; ++j) o[j] = f2bf(tile[kc + j][nl]);
        *(u16x8*)(Wt + (size_t)(nb + nl) * 768 + kb + kc) = o;
    }
}

// ---------------- QKV GEMM: xb[16384,768] @ Wt^T -> Q,K [B,H,P,64], Vt [B,H,64,P] ----------------
__global__ __launch_bounds__(256, 2) void k_qkv(const u16* __restrict__ A, const u16* __restrict__ Bt,
                                                const float* __restrict__ pos, u16* __restrict__ Qb,
                                                u16* __restrict__ Kb, u16* __restrict__ Vt) {
    __shared__ __align__(16) union SM {
        u16 stage[2][2][8192];  // [buf][A/B][128 rows x 64 k]
        u16 vt[128][136];       // epilogue transpose tile (rows 16B-aligned: 272B)
    } sm;
    const int tid = threadIdx.x;
    const int l = tid & 63, w = tid >> 6;
    const int wm = w >> 1, wn = w & 1;
    const int m0 = blockIdx.x * 128, n0 = blockIdx.y * 128;
    const int srow = l >> 3, sslot = (l & 7) ^ srow;
    const int q4 = l >> 4, lr = l & 15;

    f32x4 acc[4][4];
#pragma unroll
    for (int i = 0; i < 4; ++i)
#pragma unroll
        for (int j = 0; j < 4; ++j) acc[i][j] = (f32x4){0.f, 0.f, 0.f, 0.f};

    const size_t abase = (size_t)(m0 + srow) * 768 + sslot * 8;
    const size_t bbase = (size_t)(n0 + srow) * 768 + sslot * 8;

    // prologue stage kt=0
#pragma unroll
    for (int i = 0; i < 4; ++i) {
        int chunk = w * 4 + i;
        gload_lds16(A + abase + (size_t)chunk * 8 * 768, &sm.stage[0][0][chunk * 512]);
        gload_lds16(Bt + bbase + (size_t)chunk * 8 * 768, &sm.stage[0][1][chunk * 512]);
    }
    __syncthreads();

    int cur = 0;
    for (int kt = 0; kt < 12; ++kt) {
        if (kt < 11) {
            const size_t ko = (size_t)(kt + 1) * 64;
#pragma unroll
            for (int i = 0; i < 4; ++i) {
                int chunk = w * 4 + i;
                gload_lds16(A + abase + (size_t)chunk * 8 * 768 + ko, &sm.stage[cur ^ 1][0][chunk * 512]);
                gload_lds16(Bt + bbase + (size_t)chunk * 8 * 768 + ko, &sm.stage[cur ^ 1][1][chunk * 512]);
            }
        }
        const u16* ab = sm.stage[cur][0];
        const u16* bb = sm.stage[cur][1];
        u16x8 af[4][2], bf[4][2];
#pragma unroll
        for (int mi = 0; mi < 4; ++mi) {
            int row = wm * 64 + mi * 16 + lr;
#pragma unroll
            for (int ks = 0; ks < 2; ++ks) {
                int kc = ks * 4 + q4;
                af[mi][ks] = *(const u16x8*)(ab + row * 64 + (kc ^ (row & 7)) * 8);
            }
        }
#pragma unroll
        for (int ni = 0; ni < 4; ++ni) {
            int row = wn * 64 + ni * 16 + lr;
#pragma unroll
            for (int ks = 0; ks < 2; ++ks) {
                int kc = ks * 4 + q4;
                bf[ni][ks] = *(const u16x8*)(bb + row * 64 + (kc ^ (row & 7)) * 8);
            }
        }
#pragma unroll
        for (int mi = 0; mi < 4; ++mi)
#pragma unroll
            for (int ni = 0; ni < 4; ++ni) {
                acc[mi][ni] = mfma_bf16(af[mi][0], bf[ni][0], acc[mi][ni]);
                acc[mi][ni] = mfma_bf16(af[mi][1], bf[ni][1], acc[mi][ni]);
            }
        __syncthreads();
        cur ^= 1;
    }

    // ---- epilogue ----
    const int sec = blockIdx.y / 6;          // 0=Q 1=K 2=V
    const int dsec = n0 - sec * 768;         // col base within section
    const int bidx = m0 >> 10;
    const int prow = m0 & 1023;
    if (sec < 2) {
        // Q/K: stage [p][d] tile in LDS (+pos, rounded), then u16x8 coalesced stores
        u16* outp = sec ? Kb : Qb;
#pragma unroll
        for (int mi = 0; mi < 4; ++mi)
#pragma unroll
            for (int ni = 0; ni < 4; ++ni) {
                const int dl = wn * 64 + ni * 16 + lr;
                const int d = dsec + dl;
#pragma unroll
                for (int r = 0; r < 4; ++r) {
                    const int pl = wm * 64 + mi * 16 + q4 * 4 + r;
                    const int p = prow + pl;
                    sm.vt[pl][dl] = f2bf(acc[mi][ni][r] + pos[p * 768 + d]);
                }
            }
        __syncthreads();
#pragma unroll
        for (int it = 0; it < 8; ++it) {
            const int idx = it * 256 + tid;
            const int pl = idx >> 4, c8 = (idx & 15) * 8;
            u16x8 val = *(const u16x8*)(&sm.vt[pl][c8]);
            const int d = dsec + c8, h = d >> 6, hd = d & 63;
            *(u16x8*)(outp + (size_t)((bidx * 12 + h) * 1024 + prow + pl) * 64 + hd) = val;
        }
    } else {
        // V: transpose through LDS, write Vt[b,h,hd,p] coalesced
#pragma unroll
        for (int mi = 0; mi < 4; ++mi)
#pragma unroll
            for (int ni = 0; ni < 4; ++ni) {
                int col = wn * 64 + ni * 16 + lr;   // local d 0..127
                int d = dsec + col;
                u16x4 pk;
#pragma unroll
                for (int r = 0; r < 4; ++r) {
                    int p = prow + wm * 64 + mi * 16 + q4 * 4 + r;
                    pk[r] = f2bf(acc[mi][ni][r] + pos[p * 768 + d]);
                }
                *(u16x4*)(&sm.vt[col][wm * 64 + mi * 16 + q4 * 4]) = pk;
            }
        __syncthreads();
#pragma unroll
        for (int it = 0; it < 8; ++it) {
            int idx = it * 256 + tid;
            int dl = idx >> 4, c8 = (idx & 15) * 8;
            u16x8 val = *(const u16x8*)(&sm.vt[dl][c8]);
            int d = dsec + dl, h = d >> 6, hd = d & 63;
            *(u16x8*)(Vt + (size_t)((bidx * 12 + h) * 64 + hd) * 1024 + prow + c8) = val;
        }
    }
}

// ---------------- fused attention: QK^T + softmax + P-store + partial colsums ----------------
// PV is gone: pooled = colsum_q(P V) = (colsum_q P) V, done by k_pool.
__global__ __launch_bounds__(256, 4) void k_attn(const u16* __restrict__ Qb, const u16* __restrict__ Kb,
                                                 float* __restrict__ Pout, float* __restrict__ csws) {
    __shared__ float stats[64];  // row sums [row16*4 + wave]
    const int tid = threadIdx.x;
    const int l = tid & 63, w = tid >> 6;
    const int lr = l & 15, q4 = l >> 4;
    const int bh = blockIdx.y, qb = blockIdx.x, q0 = qb * 16;
    const u16* Qh = Qb + (size_t)bh * 65536;
    const u16* Kh = Kb + (size_t)bh * 65536;

    u16x8 qf[2];
#pragma unroll
    for (int ks = 0; ks < 2; ++ks)
        qf[ks] = *(const u16x8*)(Qh + (size_t)(q0 + lr) * 64 + ks * 32 + q4 * 8);

    f32x4 acc[16];
#pragma unroll
    for (int nf = 0; nf < 16; ++nf) acc[nf] = (f32x4){0.f, 0.f, 0.f, 0.f};

    const int kc0 = w * 256;
#pragma unroll
    for (int nf = 0; nf < 16; ++nf) {
        const u16* kp = Kh + (size_t)(kc0 + nf * 16 + lr) * 64 + q4 * 8;
        u16x8 kf0 = *(const u16x8*)kp;
        u16x8 kf1 = *(const u16x8*)(kp + 32);
        acc[nf] = mfma_bf16(qf[0], kf0, acc[nf]);
        acc[nf] = mfma_bf16(qf[1], kf1, acc[nf]);
    }

    // exp + row sum, no max subtraction (scores |s|<~4; exp2 range safe;
    // exp(s)/sum(exp(s)) identical to max-subtracted softmax).
    const float cs = 0.125f * 1.44269504f;
    float inv4[4];
#pragma unroll
    for (int r = 0; r < 4; ++r) {
        float s = 0.f;
#pragma unroll
        for (int nf = 0; nf < 16; ++nf) {
            float e = fast_exp2(acc[nf][r] * cs);
            acc[nf][r] = e;
            s += e;
        }
        s += __shfl_xor(s, 1);
        s += __shfl_xor(s, 2);
        s += __shfl_xor(s, 4);
        s += __shfl_xor(s, 8);
        if (lr == 0) stats[(q4 * 4 + r) * 4 + w] = s;
    }
    __syncthreads();
#pragma unroll
    for (int r = 0; r < 4; ++r) {
        f32x4 s4 = *(const f32x4*)(stats + (q4 * 4 + r) * 4);
        inv4[r] = 1.f / (s4[0] + s4[1] + s4[2] + s4[3]);
    }

    // normalize -> direct scalar f32 nt stores (F-probe-validated) + strip colsums
    float* Prow = Pout + ((size_t)bh * 1024 + q0) * 1024 + kc0;
    float* crow = csws + ((size_t)(bh * 64 + qb)) * 1024 + kc0;
#pragma unroll
    for (int nf = 0; nf < 16; ++nf) {
        float csum = 0.f;
#pragma unroll
        for (int r = 0; r < 4; ++r) {
            const int row = q4 * 4 + r;
            float p = acc[nf][r] * inv4[r];
            __builtin_nontemporal_store(p, &Prow[(size_t)row * 1024 + nf * 16 + lr]);
            csum += p;
        }
        csum += __shfl_xor(csum, 16);
        csum += __shfl_xor(csum, 32);
        if (l < 16) crow[nf * 16 + l] = csum;  // partial colsum over this block's 16 q-rows
    }
}

// ---------------- k_pool: per-head colsum reduce + cs @ V -> pooled ----------------
__global__ __launch_bounds__(256) void k_pool(const float* __restrict__ csws, const u16* __restrict__ Vt,
                                              float* __restrict__ pooled) {
    __shared__ float cs[1024];
    __shared__ float ps[4][64];
    const int bh = blockIdx.x, t = threadIdx.x;
    // reduce 64 partial rows (coalesced f32x4 per thread)
    f32x4 a = (f32x4){0.f, 0.f, 0.f, 0.f};
    const float* base = csws + (size_t)bh * 64 * 1024 + t * 4;
#pragma unroll 8
    for (int qb = 0; qb < 64; ++qb) a += *(const f32x4*)(base + qb * 1024);
    *(f32x4*)(cs + t * 4) = a;
    __syncthreads();
    // matvec: pooled[d] = sum_k cs[k] * V[k][d]  (Vt rows are [d][k])
    const int d = t & 63, kc = t >> 6;
    const u16* vrow = Vt + (size_t)bh * 65536 + (size_t)d * 1024 + kc * 256;
    const float* ck = cs + kc * 256;
    float s = 0.f;
#pragma unroll
    for (int k8 = 0; k8 < 32; ++k8) {
        u16x8 v = *(const u16x8*)(vrow + k8 * 8);
#pragma unroll
        for (int j = 0; j < 8; ++j) s += ck[k8 * 8 + j] * bf2f(v[j]);
    }
    ps[kc][d] = s;
    __syncthreads();
    if (t < 64) {
        const int bb = bh / 12, hh = bh % 12;
        pooled[bb * 768 + hh * 64 + t] = ps[0][t] + ps[1][t] + ps[2][t] + ps[3][t];
    }
}

// ---------------- pooled/1024 @ Wo + bo -> tmp[16,768] ----------------
__global__ __launch_bounds__(128) void k_proj(const float* __restrict__ pooled_sum,
                                              const float* __restrict__ Wo, const float* __restrict__ bo,
                                              float* __restrict__ tmp) {
    const int b = blockIdx.y, j = blockIdx.x * 128 + threadIdx.x;
    __shared__ float pr[768];
    for (int i = threadIdx.x; i < 768; i += 128) pr[i] = pooled_sum[b * 768 + i] * (1.0f / 1024.0f);
    __syncthreads();
    float s = bo[j];
#pragma unroll 4
    for (int d = 0; d < 768; ++d) s = fmaf(pr[d], Wo[d * 768 + j], s);
    tmp[b * 768 + j] = s;
}

// ---------------- tmp @ Wc + bc -> logits ----------------
__global__ __launch_bounds__(128) void k_cls(const float* __restrict__ tmp,
                                             const float* __restrict__ Wc, const float* __restrict__ bc,
                                             float* __restrict__ out) {
    const int b = blockIdx.y, c = blockIdx.x * 128 + threadIdx.x;
    __shared__ float tr[768];
    for (int i = threadIdx.x; i < 768; i += 128) tr[i] = tmp[b * 768 + i];
    __syncthreads();
    if (c >= 1000) return;
    float s = bc[c];
#pragma unroll 4
    for (int j = 0; j < 768; ++j) s = fmaf(tr[j], Wc[j * 1000 + c], s);
    out[b * 1000 + c] = s;
}

extern "C" void kernel_launch(void* const* d_in, const int* in_sizes, int n_in,
                              void* d_out, int out_size, void* d_ws, size_t ws_size,
                              hipStream_t stream) {
    const float* x    = (const float*)d_in[0];
    const float* Wqkv = (const float*)d_in[1];
    const float* pos  = (const float*)d_in[2];
    const float* Wo   = (const float*)d_in[3];
    const float* bo   = (const float*)d_in[4];
    const float* Wc   = (const float*)d_in[5];
    const float* bc   = (const float*)d_in[6];
    float* out  = (float*)d_out;
    float* attn = out + 16000;  // logits [16,1000] first, then attn_weights [16,12,1024,1024]

    char* ws = (char*)d_ws;
    u16* xb = (u16*)ws;  ws += (size_t)16384 * 768 * 2;
    u16* Wt = (u16*)ws;  ws += (size_t)2304 * 768 * 2;
    u16* Qb = (u16*)ws;  ws += (size_t)192 * 1024 * 64 * 2;
    u16* Kb = (u16*)ws;  ws += (size_t)192 * 1024 * 64 * 2;
    u16* Vt = (u16*)ws;  ws += (size_t)192 * 1024 * 64 * 2;
    float* csws = (float*)ws;  ws += (size_t)12288 * 1024 * sizeof(float);
    float* pooled = (float*)ws;  ws += 16 * 768 * sizeof(float);
    float* tmp = (float*)ws;

    k_cast_x<<<6144, 256, 0, stream>>>(x, xb);
    k_transpose_w<<<dim3(36, 12), 256, 0, stream>>>(Wqkv, Wt);
    k_qkv<<<dim3(128, 18), 256, 0, stream>>>(xb, Wt, pos, Qb, Kb, Vt);
    k_attn<<<dim3(64, 192), 256, 0, stream>>>(Qb, Kb, attn, csws);
    k_pool<<<192, 256, 0, stream>>>(csws, Vt, pooled);
    k_proj<<<dim3(6, 16), 128, 0, stream>>>(pooled, Wo, bo, tmp);
    k_cls<<<dim3(8, 16), 128, 0, stream>>>(tmp, Wc, bc, out);
}